// Round 1
// baseline (100.531 us; speedup 1.0000x reference)
//
#include <hip/hip_runtime.h>

typedef float f32x4 __attribute__((ext_vector_type(4)));

#define ZD      128      // feature dim (bytes per fp8 row, too)
#define BT      128      // block tile (128x128, 64x64 per wave)
#define D2_CUT  60.0f    // exact-path cutoff: exp(-30)~9e-14
#define D2_TRIG 70.0f    // trigger: fp8 dot err <= ~+-3 on d2 => skip implies
                         // true d2 >= 70-6 > D2_CUT (12-sigma data margin)

// ---------------------------------------------------------------------------
// Fused single kernel: one block per 128x128 upper-triangle tile (2080).
// Each block stages its own fp32 z-panels, converting to fp8 e4m3 in-register
// (HW cvt_pk) and ds_write'ing directly into the XOR-swizzled LDS layout
// (LDS[row][ch] = G[row][ch ^ (row&7)], 16B-chunk granularity) that the
// proven fragment-read path expects. Row norms (fp32, exact) land in LDS;
// the per-wave 64-row min for the bound is a shuffle butterfly (same value
// as the old min(sqmin[g],sqmin[g+1])). Class counts + p[] are computed
// lazily ONLY by waves entering the trigger branch (128 diag-quadrant waves
// + rare random triggers). The analytic diagonal term is added by tile 0 /
// wave 0 (guaranteed trigger: bound <= 0 on diagonal quadrants). out[0] is
// zeroed by a 4-byte memset node so all contributions are order-free
// atomicAdds. This removes the dep_prep dispatch, its zb8/sq/sqmin global
// round-trip, and the inter-kernel dependency gap.
// ---------------------------------------------------------------------------
__global__ __launch_bounds__(256, 4) void dep_fused(
    const float* __restrict__ z, const int* __restrict__ s,
    const float* __restrict__ norm, float* __restrict__ out,
    int T, int N)
{
    __shared__ __align__(16) unsigned char Apan[BT * ZD];   // 16KB
    __shared__ __align__(16) unsigned char Bpan[BT * ZD];   // 16KB
    __shared__ float sqA[BT];                               // 512B
    __shared__ float sqB[BT];                               // 512B

    const int tid  = threadIdx.x;
    const int wave = tid >> 6, lane = tid & 63;

    // block-uniform triangle map t -> (ti <= tj)
    const int t = blockIdx.x;
    #define TRI_BASE(x) ((x) * T - ((x) * ((x) - 1)) / 2)
    double disc = (2.0 * T + 1.0) * (2.0 * T + 1.0) - 8.0 * (double)t;
    int ti = (int)((2.0 * T + 1.0 - sqrt(disc)) * 0.5);
    if (ti < 0) ti = 0;
    if (ti > T - 1) ti = T - 1;
    while (ti + 1 < T && TRI_BASE(ti + 1) <= t) ++ti;
    while (ti > 0 && TRI_BASE(ti) > t) --ti;
    const int tj = ti + (t - TRI_BASE(ti));
    #undef TRI_BASE

    const int i0 = ti * BT, j0 = tj * BT;
    const int wi = wave >> 1, wj = wave & 1;
    const int l15 = lane & 15, quad = lane >> 4;

    // ---- fused staging: fp32 row -> fp8 LDS panel (+ exact fp32 norms) ----
    // One thread per panel-row: waves 0,1 -> A rows 0..127; waves 2,3 -> B.
    // Per-thread loads are contiguous 512B (L1-line reuse across the 8
    // chunk-groups); writes go to the swizzled chunk (gc ^ (row&7)).
    {
        const int pr  = tid & 127;
        const int isB = tid >> 7;                  // wave-uniform
        const int grow = (isB ? j0 : i0) + pr;
        unsigned char* pan = isB ? Bpan : Apan;
        const float4* zrow = (const float4*)(z + (size_t)grow * ZD);
        float ssum = 0.f;
        #pragma unroll
        for (int gc = 0; gc < 8; ++gc) {           // 8 x 16B fp8 chunks
            unsigned int w[4];
            #pragma unroll
            for (int q = 0; q < 4; ++q) {
                const float4 v = zrow[gc * 4 + q];
                ssum += v.x*v.x + v.y*v.y + v.z*v.z + v.w*v.w;
                int pk = __builtin_amdgcn_cvt_pk_fp8_f32(v.x, v.y, 0, false);
                pk     = __builtin_amdgcn_cvt_pk_fp8_f32(v.z, v.w, pk, true);
                w[q] = (unsigned int)pk;
            }
            const int dch = gc ^ (pr & 7);         // LDS-side XOR swizzle
            ((uint4*)(pan + pr * ZD))[dch] = make_uint4(w[0], w[1], w[2], w[3]);
        }
        (isB ? sqB : sqA)[pr] = ssum;
    }
    __syncthreads();

    // ---- MFMA phase: identical fragment path to the verified R9 kernel ----
    f32x4 accv[4][4];
    #pragma unroll
    for (int a = 0; a < 4; ++a)
        #pragma unroll
        for (int b = 0; b < 4; ++b)
            accv[a][b] = (f32x4){0.f, 0.f, 0.f, 0.f};

    const int sub = (quad & 1) * 8;                // 8B half within 16B chunk
    #pragma unroll
    for (int kc = 0; kc < 4; ++kc) {
        long af[4], bfr[4];
        // orig chunk = kc*2 + quad/2; row&7 == l15&7 for all fragment rows
        const int ch = (kc * 2 + (quad >> 1)) ^ (l15 & 7);
        #pragma unroll
        for (int it = 0; it < 4; ++it) {
            const int row = wi * 64 + it * 16 + l15;
            af[it] = *(const long*)(Apan + row * ZD + (ch << 4) + sub);
        }
        #pragma unroll
        for (int jt = 0; jt < 4; ++jt) {
            const int row = wj * 64 + jt * 16 + l15;
            bfr[jt] = *(const long*)(Bpan + row * ZD + (ch << 4) + sub);
        }
        #pragma unroll
        for (int it = 0; it < 4; ++it)
            #pragma unroll
            for (int jt = 0; jt < 4; ++jt)
                accv[it][jt] = __builtin_amdgcn_mfma_f32_16x16x32_fp8_fp8(
                    af[it], bfr[jt], accv[it][jt], 0, 0, 0);
    }

    // ---- fast epilogue: wave max-dot + 64-row norm mins (one butterfly) ----
    float m = -1e30f;
    #pragma unroll
    for (int it = 0; it < 4; ++it)
        #pragma unroll
        for (int jt = 0; jt < 4; ++jt) {
            const f32x4 v = accv[it][jt];
            m = fmaxf(m, fmaxf(fmaxf(v[0], v[1]), fmaxf(v[2], v[3])));
        }
    float sminA = sqA[wi * 64 + lane];
    float sminB = sqB[wj * 64 + lane];
    #pragma unroll
    for (int off = 1; off < 64; off <<= 1) {
        m     = fmaxf(m,     __shfl_xor(m, off, 64));
        sminA = fminf(sminA, __shfl_xor(sminA, off, 64));
        sminB = fminf(sminB, __shfl_xor(sminB, off, 64));
    }
    const float bound = sminA + sminB - 2.0f * m;

    if (bound < D2_TRIG) {   // wave-uniform; diag quadrants + rare triggers
        // lazy global class stats (cold path, ~130 waves total)
        int c0 = 0, c1 = 0, c2 = 0, c3 = 0;
        for (int it = lane; it < N / 4; it += 64) {
            const int4 v = ((const int4*)s)[it];
            c0 += (v.x == 0) + (v.y == 0) + (v.z == 0) + (v.w == 0);
            c1 += (v.x == 1) + (v.y == 1) + (v.z == 1) + (v.w == 1);
            c2 += (v.x == 2) + (v.y == 2) + (v.z == 2) + (v.w == 2);
            c3 += (v.x == 3) + (v.y == 3) + (v.z == 3) + (v.w == 3);
        }
        #pragma unroll
        for (int off = 1; off < 64; off <<= 1) {
            c0 += __shfl_xor(c0, off, 64);
            c1 += __shfl_xor(c1, off, 64);
            c2 += __shfl_xor(c2, off, 64);
            c3 += __shfl_xor(c3, off, 64);
        }
        const double nD = (double)N;
        const double p0 = c0 / nD, p1 = c1 / nD, p2 = c2 / nD, p3 = c3 / nD;
        const double sump2d = p0*p0 + p1*p1 + p2*p2 + p3*p3;
        const double scaled = (1.0 - exp(-1.0)) / ((double)norm[0] * nD * nD);
        const float p[4]   = {(float)p0, (float)p1, (float)p2, (float)p3};
        const float sump2  = (float)sump2d;
        const float scale  = (float)scaled;

        const int ibase = wi * 64, jbase = wj * 64;     // panel-local
        float sqj[4];
        #pragma unroll
        for (int jt = 0; jt < 4; ++jt) sqj[jt] = sqB[jbase + jt * 16 + l15];

        float local = 0.f;
        #pragma unroll
        for (int it = 0; it < 4; ++it) {
            #pragma unroll
            for (int r = 0; r < 4; ++r) {
                const int rloc = ibase + it * 16 + quad * 4 + r;  // C/D row
                const int i    = i0 + rloc;
                const float sqi = sqA[rloc];
                #pragma unroll
                for (int jt = 0; jt < 4; ++jt) {
                    const int j = j0 + jbase + jt * 16 + l15;     // C/D col
                    float d2 = sqi + sqj[jt] - 2.0f * accv[it][jt][r];
                    d2 = fmaxf(d2, 0.0f);
                    if (d2 < D2_CUT && i != j) {
                        const int si = s[i], sj = s[j];
                        const float w = (si == sj ? 1.0f : 0.0f)
                                      - p[si] - p[sj] + sump2;
                        local += w * __expf(-0.5f * d2);
                    }
                }
            }
        }
        if (ti < tj) local *= 2.0f;   // off-diag tiles count both orders

        #pragma unroll
        for (int off = 32; off > 0; off >>= 1)
            local += __shfl_down(local, off, 64);

        if (lane == 0) {
            if (local != 0.0f) atomicAdd(out, local * scale);
            if (t == 0 && wave == 0) {
                // analytic diagonal: K_z[i,i]=1; bitwise-identical math to
                // the old dep_prep (double, then one float cast)
                const double c2sum = (double)c0*c0 + (double)c1*c1
                                   + (double)c2*c2 + (double)c3*c3;
                const double diag = nD - c2sum / nD;
                atomicAdd(out, (float)(diag * scaled));
            }
        }
    }
}

extern "C" void kernel_launch(void* const* d_in, const int* in_sizes, int n_in,
                              void* d_out, int out_size, void* d_ws, size_t ws_size,
                              hipStream_t stream)
{
    const float* z    = (const float*)d_in[0];
    const int*   s    = (const int*)d_in[1];
    const float* norm = (const float*)d_in[2];
    float* out = (float*)d_out;

    const int N = in_sizes[1];       // 8192
    const int T = N / BT;            // 64

    (void)d_ws; (void)ws_size; (void)n_in; (void)out_size;

    // 4-byte memset node (stream-capturable): makes all contributions
    // order-free atomicAdds.
    hipMemsetAsync(out, 0, sizeof(float), stream);

    const int nblocks = T * (T + 1) / 2;   // 2080
    dep_fused<<<nblocks, 256, 0, stream>>>(z, s, norm, out, T, N);
}